// Round 5
// baseline (170.332 us; speedup 1.0000x reference)
//
#include <hip/hip_runtime.h>
#include <math.h>

#define BB 4
#define NN 8192
#define KNB 16
#define DD 128
#define SS 17            // K+1 (self + neighbors)
#define M_TOT (BB*NN)    // 32768
#define WPAD 136         // padded inner stride (elems) for LDS tiles

typedef __attribute__((ext_vector_type(8))) short          bf8;
typedef __attribute__((ext_vector_type(4))) float          f4;
typedef __attribute__((ext_vector_type(4))) unsigned short u16x4;

static __device__ __forceinline__ unsigned short f2bf(float f) {
    unsigned u = __builtin_bit_cast(unsigned, f);
    u += 0x7fffu + ((u >> 16) & 1u);        // round-to-nearest-even
    return (unsigned short)(u >> 16);
}
static __device__ __forceinline__ float bf2f_s(short h) {
    return __builtin_bit_cast(float, (unsigned)(unsigned short)h << 16);
}

// ---------------------------------------------------------------------------
// Transpose+convert the six 128x128 fp32 weights to bf16 W^T[n][k].
// ---------------------------------------------------------------------------
__global__ __launch_bounds__(256) void cvt_wT(
    const float* __restrict__ Wq, const float* __restrict__ Wk,
    const float* __restrict__ Wv, const float* __restrict__ Wo,
    const float* __restrict__ W1, const float* __restrict__ W2,
    unsigned short* __restrict__ out)
{
    int m = blockIdx.x >> 4;
    const float* src = (m == 0) ? Wq : (m == 1) ? Wk : (m == 2) ? Wv
                     : (m == 3) ? Wo : (m == 4) ? W1 : W2;
    unsigned short* dst = out + m * 16384;
    int o = (blockIdx.x & 15) * 1024 + threadIdx.x * 4;   // output idx [n][k]
    int n = o >> 7, k = o & 127;
    u16x4 r;
    #pragma unroll
    for (int i = 0; i < 4; ++i) r[i] = f2bf(src[(size_t)(k + i) * 128 + n]);
    *(u16x4*)(dst + o) = r;
}

// ---------------------------------------------------------------------------
// QKV projection, ZERO LDS / ZERO barriers. A-frags read directly from fp32
// X (lane's row, 2x float4 per k-step, lines collectively fully consumed);
// B-frags read directly from L2-hot bf16 W^T (96 KB; ~196 MB aggregate L2
// traffic ~= 6 us, hidden under MFMA). Removes the 5 barriers + 52 KB LDS
// of the staged version -> occupancy VGPR-bound only, waves run free.
// K and V outputs INTERLEAVED per row: kv[row][0:128]=K, [128:256]=V.
// Fragment maps (m89-verified): A[m=lane&15][k=quad*8+j],
// B[k=quad*8+j][n=lane&15], D[row=quad*4+r][col=lane&15].
// ---------------------------------------------------------------------------
__global__ __launch_bounds__(256) void qkv_kernel(
    const float* __restrict__ X, const unsigned short* __restrict__ WtT,
    const float* __restrict__ bq, const float* __restrict__ bk,
    const float* __restrict__ bv,
    unsigned short* __restrict__ qh, unsigned short* __restrict__ kv)
{
    const int tid  = threadIdx.x;
    const int row0 = blockIdx.x * 64;
    const int lane = tid & 63, wv = tid >> 6;   // wave owns rows wv*16..+15
    const int ln = lane & 15, quad = lane >> 4;

    // A-frags: direct from global fp32, convert in-reg (row = arow, quarter
    // of the row per lane; quads cover the rest).
    const int arow = row0 + wv * 16 + ln;
    bf8 afr[4];
    #pragma unroll
    for (int s = 0; s < 4; ++s) {
        const float4* xp = (const float4*)(X + (size_t)arow * DD + s * 32 + quad * 8);
        float4 x0 = xp[0], x1 = xp[1];
        bf8 a;
        a[0] = (short)f2bf(x0.x); a[1] = (short)f2bf(x0.y);
        a[2] = (short)f2bf(x0.z); a[3] = (short)f2bf(x0.w);
        a[4] = (short)f2bf(x1.x); a[5] = (short)f2bf(x1.y);
        a[6] = (short)f2bf(x1.z); a[7] = (short)f2bf(x1.w);
        afr[s] = a;
    }

    const float* biases[3] = { bq, bk, bv };
    unsigned short* outs[3] = { qh, kv, kv + 128 };
    const int strides[3] = { 128, 256, 256 };

    #pragma unroll 1
    for (int g = 0; g < 3; ++g) {
        const unsigned short* Wg = WtT + g * 16384;
        f4 acc[8] = {};
        #pragma unroll
        for (int t = 0; t < 8; ++t) {
            bf8 bfr[4];
            #pragma unroll
            for (int s = 0; s < 4; ++s)
                bfr[s] = *(const bf8*)(Wg + (size_t)(t * 16 + ln) * 128 + s * 32 + quad * 8);
            #pragma unroll
            for (int s = 0; s < 4; ++s)
                acc[t] = __builtin_amdgcn_mfma_f32_16x16x32_bf16(afr[s], bfr[s], acc[t], 0, 0, 0);
        }

        const float* bias = biases[g];
        unsigned short* Y = outs[g];
        const int st = strides[g];
        #pragma unroll
        for (int t = 0; t < 8; ++t) {
            int col = t * 16 + ln;
            float bc = bias[col];
            #pragma unroll
            for (int r = 0; r < 4; ++r) {
                int row = row0 + wv * 16 + quad * 4 + r;
                Y[(size_t)row * st + col] = f2bf(acc[t][r] + bc);
            }
        }
    }
}

// ---------------------------------------------------------------------------
// Attention, register-resident, S-SPLIT (round-4 proven: 32 lanes/vertex,
// sp owns half the 17 rows; cross-half combine via shfl_xor(16)).
// NEW: all 9 V loads are ISSUED BEFORE the softmax — their L2 latency
// (~200-300 cyc) overlaps the ~50 VALU ops of softmax instead of being
// fully exposed after it. Loads unguarded (round-1 lesson); masking
// arithmetic. 8 vertices/block, 4096 blocks; batch pinned to XCD pair.
// ---------------------------------------------------------------------------
__global__ __launch_bounds__(256) void attn_kernel(
    const unsigned short* __restrict__ Qh, const unsigned short* __restrict__ KV,
    const int* __restrict__ nbr, const int* __restrict__ vlen,
    unsigned short* __restrict__ Ctx)
{
    const int tid  = threadIdx.x;
    const int vloc = tid >> 5;        // 0..7
    const int sp   = (tid >> 4) & 1;  // s-half
    const int ln16 = tid & 15;        // 8-dim slot
    const int blk  = blockIdx.x;
    const int b    = (blk & 7) >> 1;                 // batch from XCD pair
    const int j    = ((blk >> 3) << 1) | (blk & 1);  // within-batch group 0..1023
    const int v    = b * NN + j * 8 + vloc;
    const int len  = vlen[v];         // rows 0..len valid (len in [0,16))

    // q fragment: 8 dims (lane's head = ln16>>2)
    bf8 q8 = *(const bf8*)(Qh + (size_t)v * DD + ln16 * 8);
    float qf[8];
    #pragma unroll
    for (int i = 0; i < 8; ++i) qf[i] = bf2f_s(q8[i]);

    // This half's 9 rows. sp0: {self, nbr0..7}; sp1: {nbr8..15, self-dummy}
    int rows[9];
    {
        const int4* np = (const int4*)(nbr + (size_t)v * KNB);
        if (sp == 0) {
            rows[0] = v;
            int4 a = np[0], c = np[1];
            rows[1] = b * NN + a.x; rows[2] = b * NN + a.y;
            rows[3] = b * NN + a.z; rows[4] = b * NN + a.w;
            rows[5] = b * NN + c.x; rows[6] = b * NN + c.y;
            rows[7] = b * NN + c.z; rows[8] = b * NN + c.w;
        } else {
            int4 a = np[2], c = np[3];
            rows[0] = b * NN + a.x; rows[1] = b * NN + a.y;
            rows[2] = b * NN + a.z; rows[3] = b * NN + a.w;
            rows[4] = b * NN + c.x; rows[5] = b * NN + c.y;
            rows[6] = b * NN + c.z; rows[7] = b * NN + c.w;
            rows[8] = v;            // dummy: s=17 > len always -> weight 0
        }
    }
    const int s0 = sp * 9;

    // K loads (batched, unguarded)
    bf8 k8[9];
    #pragma unroll
    for (int i = 0; i < 9; ++i)
        k8[i] = *(const bf8*)(KV + (size_t)rows[i] * 256 + ln16 * 8);

    // scores (frees k8 progressively)
    float sc[9];
    #pragma unroll
    for (int i = 0; i < 9; ++i) {
        float p = 0.f;
        #pragma unroll
        for (int d = 0; d < 8; ++d) p = fmaf(qf[d], bf2f_s(k8[i][d]), p);
        p += __shfl_xor(p, 1, 4);
        p += __shfl_xor(p, 2, 4);
        sc[i] = (s0 + i <= len) ? p * 0.17677669529663687f : -1.0e9f;  // 1/sqrt(32)
    }

    // V loads issued NOW — latency hides under the softmax below.
    bf8 v8[9];
    #pragma unroll
    for (int i = 0; i < 9; ++i)
        v8[i] = *(const bf8*)(KV + (size_t)rows[i] * 256 + 128 + ln16 * 8);

    // Softmax across both halves: max/sum via shfl_xor(16).
    float m = sc[0];
    #pragma unroll
    for (int i = 1; i < 9; ++i) m = fmaxf(m, sc[i]);
    m = fmaxf(m, __shfl_xor(m, 16));
    float sum = 0.f;
    #pragma unroll
    for (int i = 0; i < 9; ++i) {
        float e = __expf(sc[i] - m);    // invalid: exp(-1e9 - m) == 0
        sc[i] = e;
        sum += e;
    }
    sum += __shfl_xor(sum, 16);
    const float inv = 1.f / sum;

    // Pass 2: weighted V accumulate from registers.
    float acc[8] = {};
    #pragma unroll
    for (int i = 0; i < 9; ++i) {
        float w = sc[i] * inv;
        #pragma unroll
        for (int d = 0; d < 8; ++d) acc[d] = fmaf(w, bf2f_s(v8[i][d]), acc[d]);
    }
    // combine halves
    #pragma unroll
    for (int d = 0; d < 8; ++d) acc[d] += __shfl_xor(acc[d], 16);

    if (sp == 0) {
        bf8 r;
        #pragma unroll
        for (int d = 0; d < 8; ++d) r[d] = (short)f2bf(acc[d]);
        *(bf8*)(Ctx + (size_t)v * DD + ln16 * 8) = r;
    }
}

// ---------------------------------------------------------------------------
// Fused Wo + FFN(W1,relu,W2): ctx -> out, chained through one LDS tile.
// 64 rows/block, 4 waves. NEW: B-frags read DIRECTLY from L2-hot weights
// (round-3 validated) — Wb LDS tile gone: LDS 52.2 -> 17.4 KB, barriers
// 6 -> 5, occupancy no longer LDS-capped.
// ---------------------------------------------------------------------------
__global__ __launch_bounds__(256) void ffn_kernel(
    const unsigned short* __restrict__ Ctxg, const unsigned short* __restrict__ WtT3,
    const float* __restrict__ bo, const float* __restrict__ b1,
    const float* __restrict__ b2, float* __restrict__ Out)
{
    __shared__ unsigned short Ct[64 * WPAD];    // 17408 B — the only LDS

    const int tid  = threadIdx.x;
    const int row0 = blockIdx.x * 64;

    // Stage ctx tile (bf16, coalesced 16 B)
    {
        const bf8* Cg = (const bf8*)(Ctxg + (size_t)row0 * DD);
        #pragma unroll
        for (int i = 0; i < 4; ++i) {
            int idx = tid + i * 256;
            int r = idx >> 4, c8 = idx & 15;
            *(bf8*)(Ct + r * WPAD + c8 * 8) = Cg[idx];
        }
    }

    const int lane = tid & 63, wv = tid >> 6;
    const int ln = lane & 15, quad = lane >> 4;
    const float* biases[3] = { bo, b1, b2 };
    __syncthreads();    // Ct staged

    #pragma unroll 1
    for (int g = 0; g < 3; ++g) {
        bf8 afr[4];
        #pragma unroll
        for (int s = 0; s < 4; ++s)
            afr[s] = *(const bf8*)(Ct + (wv * 16 + ln) * WPAD + s * 32 + quad * 8);

        const unsigned short* Wg = WtT3 + g * 16384;
        f4 acc[8] = {};
        #pragma unroll
        for (int t = 0; t < 8; ++t) {
            bf8 bfr[4];
            #pragma unroll
            for (int s = 0; s < 4; ++s)
                bfr[s] = *(const bf8*)(Wg + (size_t)(t * 16 + ln) * 128 + s * 32 + quad * 8);
            #pragma unroll
            for (int s = 0; s < 4; ++s)
                acc[t] = __builtin_amdgcn_mfma_f32_16x16x32_bf16(afr[s], bfr[s], acc[t], 0, 0, 0);
        }

        const float* bias = biases[g];
        if (g == 2) {
            #pragma unroll
            for (int t = 0; t < 8; ++t) {
                int col = t * 16 + ln;
                float bc = bias[col];
                #pragma unroll
                for (int r = 0; r < 4; ++r) {
                    int row = row0 + wv * 16 + quad * 4 + r;
                    Out[(size_t)row * DD + col] = acc[t][r] + bc;
                }
            }
        } else {
            __syncthreads();   // all waves done reading Ct for this g
            #pragma unroll
            for (int t = 0; t < 8; ++t) {
                int col = t * 16 + ln;
                float bc = bias[col];
                #pragma unroll
                for (int r = 0; r < 4; ++r) {
                    int rloc = wv * 16 + quad * 4 + r;
                    float vv = acc[t][r] + bc;
                    if (g == 1) vv = fmaxf(vv, 0.f);
                    Ct[rloc * WPAD + col] = f2bf(vv);
                }
            }
            __syncthreads();   // new Ct visible before next g's afr reads
        }
    }
}

// ---------------------------------------------------------------------------
extern "C" void kernel_launch(void* const* d_in, const int* in_sizes, int n_in,
                              void* d_out, int out_size, void* d_ws, size_t ws_size,
                              hipStream_t stream)
{
    const float* vf   = (const float*)d_in[0];
    const int*   nbr  = (const int*)  d_in[1];
    const int*   vlen = (const int*)  d_in[2];
    const float* Wq   = (const float*)d_in[3];
    const float* bq   = (const float*)d_in[4];
    const float* Wk   = (const float*)d_in[5];
    const float* bk   = (const float*)d_in[6];
    const float* Wv   = (const float*)d_in[7];
    const float* bv   = (const float*)d_in[8];
    const float* Wo   = (const float*)d_in[9];
    const float* bo   = (const float*)d_in[10];
    const float* W1   = (const float*)d_in[11];
    const float* b1   = (const float*)d_in[12];
    const float* W2   = (const float*)d_in[13];
    const float* b2   = (const float*)d_in[14];

    float* out = (float*)d_out;

    const size_t SZ = (size_t)M_TOT * DD;
    unsigned short* WtT = (unsigned short*)d_ws;    // 6 x 16384 bf16
    unsigned short* qh  = WtT + 6 * 16384;
    unsigned short* kv  = qh + SZ;                  // interleaved K|V, 2*SZ
    unsigned short* ctx = kv + 2 * SZ;

    cvt_wT<<<96, 256, 0, stream>>>(Wq, Wk, Wv, Wo, W1, W2, WtT);

    qkv_kernel<<<M_TOT / 64, 256, 0, stream>>>(vf, WtT, bq, bk, bv, qh, kv);

    attn_kernel<<<M_TOT / 8, 256, 0, stream>>>(qh, kv, nbr, vlen, ctx);

    ffn_kernel<<<M_TOT / 64, 256, 0, stream>>>(ctx, WtT + 3 * 16384, bo, b1, b2, out);
}

// Round 6
// 135.953 us; speedup vs baseline: 1.2529x; 1.2529x over previous
//
#include <hip/hip_runtime.h>
#include <math.h>

#define BB 4
#define NN 8192
#define KNB 16
#define DD 128
#define SS 17            // K+1 (self + neighbors)
#define M_TOT (BB*NN)    // 32768
#define WPAD 136         // padded inner stride (elems) for LDS tiles

typedef __attribute__((ext_vector_type(8))) short          bf8;
typedef __attribute__((ext_vector_type(4))) float          f4;
typedef __attribute__((ext_vector_type(4))) unsigned short u16x4;

static __device__ __forceinline__ unsigned short f2bf(float f) {
    unsigned u = __builtin_bit_cast(unsigned, f);
    u += 0x7fffu + ((u >> 16) & 1u);        // round-to-nearest-even
    return (unsigned short)(u >> 16);
}
static __device__ __forceinline__ float bf2f_s(short h) {
    return __builtin_bit_cast(float, (unsigned)(unsigned short)h << 16);
}

// ---------------------------------------------------------------------------
// Transpose+convert the six 128x128 fp32 weights to bf16 W^T[n][k].
// ---------------------------------------------------------------------------
__global__ __launch_bounds__(256) void cvt_wT(
    const float* __restrict__ Wq, const float* __restrict__ Wk,
    const float* __restrict__ Wv, const float* __restrict__ Wo,
    const float* __restrict__ W1, const float* __restrict__ W2,
    unsigned short* __restrict__ out)
{
    int m = blockIdx.x >> 4;
    const float* src = (m == 0) ? Wq : (m == 1) ? Wk : (m == 2) ? Wv
                     : (m == 3) ? Wo : (m == 4) ? W1 : W2;
    unsigned short* dst = out + m * 16384;
    int o = (blockIdx.x & 15) * 1024 + threadIdx.x * 4;   // output idx [n][k]
    int n = o >> 7, k = o & 127;
    u16x4 r;
    #pragma unroll
    for (int i = 0; i < 4; ++i) r[i] = f2bf(src[(size_t)(k + i) * 128 + n]);
    *(u16x4*)(dst + o) = r;
}

// ---------------------------------------------------------------------------
// Fused fp32->bf16 convert + QKV projection (round-4 proven: LDS-staged).
// NOTE (round-5 lesson): do NOT read MFMA B-fragments straight from global —
// the fragment lane pattern (256 B stride, 64 B chunks) shatters each load
// into ~16 L2 requests. Staging pays the badly-shaped read ONCE per block,
// coalesced, into LDS where the fragment pattern is free.
// 64 rows/block, 4 waves; X staged once, afr persistent across 3 GEMMs.
// K and V outputs INTERLEAVED per row: kv[row][0:128]=K, [128:256]=V.
// Fragment maps (m89-verified): A[m=lane&15][k=quad*8+j],
// B[k=quad*8+j][n=lane&15], D[row=quad*4+r][col=lane&15].
// LDS 17.4 + 34.8 = 52.2 KB -> 3 blocks/CU.
// ---------------------------------------------------------------------------
__global__ __launch_bounds__(256) void qkv_kernel(
    const float* __restrict__ X, const unsigned short* __restrict__ WtT,
    const float* __restrict__ bq, const float* __restrict__ bk,
    const float* __restrict__ bv,
    unsigned short* __restrict__ qh, unsigned short* __restrict__ kv)
{
    __shared__ unsigned short Xs[64 * WPAD];    // 17408 B
    __shared__ unsigned short Wb[128 * WPAD];   // 34816 B

    const int tid  = threadIdx.x;
    const int row0 = blockIdx.x * 64;

    // Stage X tile fp32 -> bf16 (coalesced float4 reads)
    {
        const float4* Xg = (const float4*)(X + (size_t)row0 * DD);
        #pragma unroll
        for (int i = 0; i < 8; ++i) {
            int idx = tid + i * 256;            // 0..2047
            int r = idx >> 5, c4 = idx & 31;
            float4 v = Xg[idx];
            u16x4 u;
            u[0] = f2bf(v.x); u[1] = f2bf(v.y); u[2] = f2bf(v.z); u[3] = f2bf(v.w);
            *(u16x4*)(Xs + r * WPAD + c4 * 4) = u;
        }
    }
    // Stage Wq^T
    #pragma unroll
    for (int i = 0; i < 8; ++i) {
        int c = tid + i * 256;
        int n = c >> 4, k8 = c & 15;
        *(bf8*)(Wb + n * WPAD + k8 * 8) = ((const bf8*)WtT)[c];
    }

    const int lane = tid & 63, wv = tid >> 6;   // wave owns rows wv*16..+15
    const int ln = lane & 15, quad = lane >> 4;
    __syncthreads();

    // A-frags: persistent across the 3 GEMMs (4 k-steps, 16 regs)
    bf8 afr[4];
    #pragma unroll
    for (int s = 0; s < 4; ++s)
        afr[s] = *(const bf8*)(Xs + (wv * 16 + ln) * WPAD + s * 32 + quad * 8);

    const float* biases[3] = { bq, bk, bv };
    unsigned short* outs[3] = { qh, kv, kv + 128 };
    const int strides[3] = { 128, 256, 256 };

    #pragma unroll 1
    for (int g = 0; g < 3; ++g) {
        if (g > 0) {
            __syncthreads();   // all waves done reading Wb for g-1
            const bf8* Wn = (const bf8*)(WtT + g * 16384);
            #pragma unroll
            for (int i = 0; i < 8; ++i) {
                int c = tid + i * 256;
                int n = c >> 4, k8 = c & 15;
                *(bf8*)(Wb + n * WPAD + k8 * 8) = Wn[c];
            }
            __syncthreads();
        }

        f4 acc[8] = {};
        #pragma unroll
        for (int t = 0; t < 8; ++t) {
            bf8 bfr[4];
            #pragma unroll
            for (int s = 0; s < 4; ++s)
                bfr[s] = *(const bf8*)(Wb + (t * 16 + ln) * WPAD + s * 32 + quad * 8);
            #pragma unroll
            for (int s = 0; s < 4; ++s)
                acc[t] = __builtin_amdgcn_mfma_f32_16x16x32_bf16(afr[s], bfr[s], acc[t], 0, 0, 0);
        }

        const float* bias = biases[g];
        unsigned short* Y = outs[g];
        const int st = strides[g];
        #pragma unroll
        for (int t = 0; t < 8; ++t) {
            int col = t * 16 + ln;
            float bc = bias[col];
            #pragma unroll
            for (int r = 0; r < 4; ++r) {
                int row = row0 + wv * 16 + quad * 4 + r;
                Y[(size_t)row * st + col] = f2bf(acc[t][r] + bc);
            }
        }
    }
}

// ---------------------------------------------------------------------------
// Attention, register-resident, S-SPLIT (round-4 proven: 32 lanes/vertex,
// sp owns half the 17 rows; cross-half combine via shfl_xor(16)).
// RETAINED from round 5: all 9 V loads ISSUED BEFORE the softmax — their
// L2 latency overlaps the ~50 VALU ops of softmax instead of being fully
// exposed after it. Loads unguarded (round-1 lesson); masking arithmetic.
// 8 vertices/block, 4096 blocks; batch pinned to XCD pair.
// ---------------------------------------------------------------------------
__global__ __launch_bounds__(256) void attn_kernel(
    const unsigned short* __restrict__ Qh, const unsigned short* __restrict__ KV,
    const int* __restrict__ nbr, const int* __restrict__ vlen,
    unsigned short* __restrict__ Ctx)
{
    const int tid  = threadIdx.x;
    const int vloc = tid >> 5;        // 0..7
    const int sp   = (tid >> 4) & 1;  // s-half
    const int ln16 = tid & 15;        // 8-dim slot
    const int blk  = blockIdx.x;
    const int b    = (blk & 7) >> 1;                 // batch from XCD pair
    const int j    = ((blk >> 3) << 1) | (blk & 1);  // within-batch group 0..1023
    const int v    = b * NN + j * 8 + vloc;
    const int len  = vlen[v];         // rows 0..len valid (len in [0,16))

    // q fragment: 8 dims (lane's head = ln16>>2)
    bf8 q8 = *(const bf8*)(Qh + (size_t)v * DD + ln16 * 8);
    float qf[8];
    #pragma unroll
    for (int i = 0; i < 8; ++i) qf[i] = bf2f_s(q8[i]);

    // This half's 9 rows. sp0: {self, nbr0..7}; sp1: {nbr8..15, self-dummy}
    int rows[9];
    {
        const int4* np = (const int4*)(nbr + (size_t)v * KNB);
        if (sp == 0) {
            rows[0] = v;
            int4 a = np[0], c = np[1];
            rows[1] = b * NN + a.x; rows[2] = b * NN + a.y;
            rows[3] = b * NN + a.z; rows[4] = b * NN + a.w;
            rows[5] = b * NN + c.x; rows[6] = b * NN + c.y;
            rows[7] = b * NN + c.z; rows[8] = b * NN + c.w;
        } else {
            int4 a = np[2], c = np[3];
            rows[0] = b * NN + a.x; rows[1] = b * NN + a.y;
            rows[2] = b * NN + a.z; rows[3] = b * NN + a.w;
            rows[4] = b * NN + c.x; rows[5] = b * NN + c.y;
            rows[6] = b * NN + c.z; rows[7] = b * NN + c.w;
            rows[8] = v;            // dummy: s=17 > len always -> weight 0
        }
    }
    const int s0 = sp * 9;

    // K loads (batched, unguarded)
    bf8 k8[9];
    #pragma unroll
    for (int i = 0; i < 9; ++i)
        k8[i] = *(const bf8*)(KV + (size_t)rows[i] * 256 + ln16 * 8);

    // scores (frees k8 progressively)
    float sc[9];
    #pragma unroll
    for (int i = 0; i < 9; ++i) {
        float p = 0.f;
        #pragma unroll
        for (int d = 0; d < 8; ++d) p = fmaf(qf[d], bf2f_s(k8[i][d]), p);
        p += __shfl_xor(p, 1, 4);
        p += __shfl_xor(p, 2, 4);
        sc[i] = (s0 + i <= len) ? p * 0.17677669529663687f : -1.0e9f;  // 1/sqrt(32)
    }

    // V loads issued NOW — latency hides under the softmax below.
    bf8 v8[9];
    #pragma unroll
    for (int i = 0; i < 9; ++i)
        v8[i] = *(const bf8*)(KV + (size_t)rows[i] * 256 + 128 + ln16 * 8);

    // Softmax across both halves: max/sum via shfl_xor(16).
    float m = sc[0];
    #pragma unroll
    for (int i = 1; i < 9; ++i) m = fmaxf(m, sc[i]);
    m = fmaxf(m, __shfl_xor(m, 16));
    float sum = 0.f;
    #pragma unroll
    for (int i = 0; i < 9; ++i) {
        float e = __expf(sc[i] - m);    // invalid: exp(-1e9 - m) == 0
        sc[i] = e;
        sum += e;
    }
    sum += __shfl_xor(sum, 16);
    const float inv = 1.f / sum;

    // Pass 2: weighted V accumulate from registers.
    float acc[8] = {};
    #pragma unroll
    for (int i = 0; i < 9; ++i) {
        float w = sc[i] * inv;
        #pragma unroll
        for (int d = 0; d < 8; ++d) acc[d] = fmaf(w, bf2f_s(v8[i][d]), acc[d]);
    }
    // combine halves
    #pragma unroll
    for (int d = 0; d < 8; ++d) acc[d] += __shfl_xor(acc[d], 16);

    if (sp == 0) {
        bf8 r;
        #pragma unroll
        for (int d = 0; d < 8; ++d) r[d] = (short)f2bf(acc[d]);
        *(bf8*)(Ctx + (size_t)v * DD + ln16 * 8) = r;
    }
}

// ---------------------------------------------------------------------------
// Fused Wo + FFN(W1,relu,W2): ctx -> out, chained through one LDS tile.
// 64 rows/block, 4 waves, wave tile 16x128. LDS 52.2 KB -> 3 blocks/CU.
// (round-4 proven version: BOTH Ct and Wb LDS-staged — see round-5 lesson
// on fragment-pattern request amplification.)
// ---------------------------------------------------------------------------
__global__ __launch_bounds__(256) void ffn_kernel(
    const unsigned short* __restrict__ Ctxg, const unsigned short* __restrict__ WtT3,
    const float* __restrict__ bo, const float* __restrict__ b1,
    const float* __restrict__ b2, float* __restrict__ Out)
{
    __shared__ unsigned short Ct[64 * WPAD];
    __shared__ unsigned short Wb[128 * WPAD];

    const int tid  = threadIdx.x;
    const int row0 = blockIdx.x * 64;

    {
        const bf8* Cg = (const bf8*)(Ctxg + (size_t)row0 * DD);
        #pragma unroll
        for (int i = 0; i < 4; ++i) {
            int idx = tid + i * 256;
            int r = idx >> 4, c8 = idx & 15;
            *(bf8*)(Ct + r * WPAD + c8 * 8) = Cg[idx];
        }
    }
    #pragma unroll
    for (int i = 0; i < 8; ++i) {
        int c = tid + i * 256;
        int n = c >> 4, k8 = c & 15;
        *(bf8*)(Wb + n * WPAD + k8 * 8) = ((const bf8*)WtT3)[c];
    }

    const int lane = tid & 63, wv = tid >> 6;
    const int ln = lane & 15, quad = lane >> 4;
    const float* biases[3] = { bo, b1, b2 };
    __syncthreads();

    #pragma unroll 1
    for (int g = 0; g < 3; ++g) {
        bf8 afr[4];
        #pragma unroll
        for (int s = 0; s < 4; ++s)
            afr[s] = *(const bf8*)(Ct + (wv * 16 + ln) * WPAD + s * 32 + quad * 8);

        f4 acc[8] = {};
        #pragma unroll
        for (int t = 0; t < 8; ++t) {
            bf8 bfr[4];
            #pragma unroll
            for (int s = 0; s < 4; ++s)
                bfr[s] = *(const bf8*)(Wb + (t * 16 + ln) * WPAD + s * 32 + quad * 8);
            #pragma unroll
            for (int s = 0; s < 4; ++s)
                acc[t] = __builtin_amdgcn_mfma_f32_16x16x32_bf16(afr[s], bfr[s], acc[t], 0, 0, 0);
        }

        __syncthreads();   // everyone done reading Ct & Wb

        const float* bias = biases[g];
        if (g == 2) {
            #pragma unroll
            for (int t = 0; t < 8; ++t) {
                int col = t * 16 + ln;
                float bc = bias[col];
                #pragma unroll
                for (int r = 0; r < 4; ++r) {
                    int row = row0 + wv * 16 + quad * 4 + r;
                    Out[(size_t)row * DD + col] = acc[t][r] + bc;
                }
            }
        } else {
            const bf8* Wn = (const bf8*)(WtT3 + (g + 1) * 16384);
            #pragma unroll
            for (int i = 0; i < 8; ++i) {
                int c = tid + i * 256;
                int n = c >> 4, k8 = c & 15;
                *(bf8*)(Wb + n * WPAD + k8 * 8) = Wn[c];
            }
            #pragma unroll
            for (int t = 0; t < 8; ++t) {
                int col = t * 16 + ln;
                float bc = bias[col];
                #pragma unroll
                for (int r = 0; r < 4; ++r) {
                    int rloc = wv * 16 + quad * 4 + r;
                    float vv = acc[t][r] + bc;
                    if (g == 1) vv = fmaxf(vv, 0.f);
                    Ct[rloc * WPAD + col] = f2bf(vv);
                }
            }
            __syncthreads();
        }
    }
}

// ---------------------------------------------------------------------------
extern "C" void kernel_launch(void* const* d_in, const int* in_sizes, int n_in,
                              void* d_out, int out_size, void* d_ws, size_t ws_size,
                              hipStream_t stream)
{
    const float* vf   = (const float*)d_in[0];
    const int*   nbr  = (const int*)  d_in[1];
    const int*   vlen = (const int*)  d_in[2];
    const float* Wq   = (const float*)d_in[3];
    const float* bq   = (const float*)d_in[4];
    const float* Wk   = (const float*)d_in[5];
    const float* bk   = (const float*)d_in[6];
    const float* Wv   = (const float*)d_in[7];
    const float* bv   = (const float*)d_in[8];
    const float* Wo   = (const float*)d_in[9];
    const float* bo   = (const float*)d_in[10];
    const float* W1   = (const float*)d_in[11];
    const float* b1   = (const float*)d_in[12];
    const float* W2   = (const float*)d_in[13];
    const float* b2   = (const float*)d_in[14];

    float* out = (float*)d_out;

    const size_t SZ = (size_t)M_TOT * DD;
    unsigned short* WtT = (unsigned short*)d_ws;    // 6 x 16384 bf16
    unsigned short* qh  = WtT + 6 * 16384;
    unsigned short* kv  = qh + SZ;                  // interleaved K|V, 2*SZ
    unsigned short* ctx = kv + 2 * SZ;

    cvt_wT<<<96, 256, 0, stream>>>(Wq, Wk, Wv, Wo, W1, W2, WtT);

    qkv_kernel<<<M_TOT / 64, 256, 0, stream>>>(vf, WtT, bq, bk, bv, qh, kv);

    attn_kernel<<<M_TOT / 8, 256, 0, stream>>>(qh, kv, nbr, vlen, ctx);

    ffn_kernel<<<M_TOT / 64, 256, 0, stream>>>(ctx, WtT + 3 * 16384, bo, b1, b2, out);
}

// Round 7
// 135.578 us; speedup vs baseline: 1.2563x; 1.0028x over previous
//
#include <hip/hip_runtime.h>
#include <math.h>

#define BB 4
#define NN 8192
#define KNB 16
#define DD 128
#define SS 17            // K+1 (self + neighbors)
#define M_TOT (BB*NN)    // 32768
#define WPAD 136         // padded inner stride (elems) for LDS tiles

typedef __attribute__((ext_vector_type(8))) short          bf8;
typedef __attribute__((ext_vector_type(4))) float          f4;
typedef __attribute__((ext_vector_type(4))) unsigned short u16x4;

static __device__ __forceinline__ unsigned short f2bf(float f) {
    unsigned u = __builtin_bit_cast(unsigned, f);
    u += 0x7fffu + ((u >> 16) & 1u);        // round-to-nearest-even
    return (unsigned short)(u >> 16);
}
static __device__ __forceinline__ float bf2f_s(short h) {
    return __builtin_bit_cast(float, (unsigned)(unsigned short)h << 16);
}

// ---------------------------------------------------------------------------
// Convert weights. Blocks 0..95: six 128x128 fp32 weights -> bf16 W^T[n][k]
// (slots 0..5: WqT,WkT,WvT,WoT,W1T,W2T). Blocks 96..111: Wo -> bf16
// ROW-MAJOR (slot 6) — B-operand for the Wm=Wo@W1 fold GEMM in qkv.
// ---------------------------------------------------------------------------
__global__ __launch_bounds__(256) void cvt_wT(
    const float* __restrict__ Wq, const float* __restrict__ Wk,
    const float* __restrict__ Wv, const float* __restrict__ Wo,
    const float* __restrict__ W1, const float* __restrict__ W2,
    unsigned short* __restrict__ out)
{
    const int blk = blockIdx.x;
    if (blk < 96) {
        int m = blk >> 4;
        const float* src = (m == 0) ? Wq : (m == 1) ? Wk : (m == 2) ? Wv
                         : (m == 3) ? Wo : (m == 4) ? W1 : W2;
        unsigned short* dst = out + m * 16384;
        int o = (blk & 15) * 1024 + threadIdx.x * 4;   // output idx [n][k]
        int n = o >> 7, k = o & 127;
        u16x4 r;
        #pragma unroll
        for (int i = 0; i < 4; ++i) r[i] = f2bf(src[(size_t)(k + i) * 128 + n]);
        *(u16x4*)(dst + o) = r;
    } else {
        // plain coalesced convert: Wo row-major -> slot 6
        int o = (blk - 96) * 1024 + threadIdx.x * 4;
        float4 v = *(const float4*)(Wo + o);
        u16x4 r;
        r[0] = f2bf(v.x); r[1] = f2bf(v.y); r[2] = f2bf(v.z); r[3] = f2bf(v.w);
        *(u16x4*)(out + 6 * 16384 + o) = r;
    }
}

// ---------------------------------------------------------------------------
// Fused fp32->bf16 convert + QKV projection (round-4/6 proven: LDS-staged;
// round-5 lesson: NEVER read MFMA B-frags straight from global — fragment
// lane pattern shatters into ~16 L2 requests; stage coalesced into LDS).
// K and V outputs INTERLEAVED per row: kv[row][0:128]=K, [128:256]=V.
// Fragment maps (m89-verified): A[m=lane&15][k=quad*8+j],
// B[k=quad*8+j][n=lane&15], D[row=quad*4+r][col=lane&15].
// PIGGYBACK blocks (schedule into the grid tail, ~free):
//   512,513: WmT = (Wo@W1)^T bf16 via the same GEMM template
//            (A = W1T slot 4, B = Wo row-major slot 6)
//   514    : bm = bo@W1 + b1 (fp32)
// These feed the folded 2-GEMM ffn; consumed only after qkv completes.
// ---------------------------------------------------------------------------
__global__ __launch_bounds__(256) void qkv_kernel(
    const float* __restrict__ X, const unsigned short* __restrict__ WtT,
    const float* __restrict__ bq, const float* __restrict__ bk,
    const float* __restrict__ bv,
    const float* __restrict__ W1f, const float* __restrict__ bo,
    const float* __restrict__ b1,
    unsigned short* __restrict__ qh, unsigned short* __restrict__ kv,
    unsigned short* __restrict__ WmT, float* __restrict__ bm)
{
    __shared__ unsigned short Xs[64 * WPAD];    // 17408 B
    __shared__ unsigned short Wb[128 * WPAD];   // 34816 B

    const int tid = threadIdx.x;
    const int blk = blockIdx.x;

    if (blk >= 512) {
        if (blk == 514) {           // bm[e] = b1[e] + sum_d bo[d]*W1[d][e]
            if (tid < 128) {
                float a = b1[tid];
                for (int d = 0; d < 128; ++d)
                    a = fmaf(bo[d], W1f[(size_t)d * 128 + tid], a);
                bm[tid] = a;
            }
            return;
        }
        // WmT[e][hk] = sum_d W1T[e][d] * Wo[hk][d]  (64 rows per block)
        const int row0 = (blk - 512) * 64;
        {
            const bf8* Ag = (const bf8*)(WtT + 4 * 16384 + (size_t)row0 * 128);
            #pragma unroll
            for (int i = 0; i < 4; ++i) {
                int idx = tid + i * 256;
                int r = idx >> 4, c8 = idx & 15;
                *(bf8*)(Xs + r * WPAD + c8 * 8) = Ag[idx];
            }
            const bf8* Bg = (const bf8*)(WtT + 6 * 16384);
            #pragma unroll
            for (int i = 0; i < 8; ++i) {
                int c = tid + i * 256;
                int n = c >> 4, k8 = c & 15;
                *(bf8*)(Wb + n * WPAD + k8 * 8) = Bg[c];
            }
        }
        __syncthreads();
        const int lane = tid & 63, wv = tid >> 6;
        const int ln = lane & 15, quad = lane >> 4;
        bf8 afr[4];
        #pragma unroll
        for (int s = 0; s < 4; ++s)
            afr[s] = *(const bf8*)(Xs + (wv * 16 + ln) * WPAD + s * 32 + quad * 8);
        f4 acc[8] = {};
        #pragma unroll
        for (int t = 0; t < 8; ++t) {
            bf8 bfr[4];
            #pragma unroll
            for (int s = 0; s < 4; ++s)
                bfr[s] = *(const bf8*)(Wb + (t * 16 + ln) * WPAD + s * 32 + quad * 8);
            #pragma unroll
            for (int s = 0; s < 4; ++s)
                acc[t] = __builtin_amdgcn_mfma_f32_16x16x32_bf16(afr[s], bfr[s], acc[t], 0, 0, 0);
        }
        #pragma unroll
        for (int t = 0; t < 8; ++t) {
            int col = t * 16 + ln;
            #pragma unroll
            for (int r = 0; r < 4; ++r) {
                int row = row0 + wv * 16 + quad * 4 + r;
                WmT[(size_t)row * 128 + col] = f2bf(acc[t][r]);
            }
        }
        return;
    }

    const int row0 = blk * 64;

    // Stage X tile fp32 -> bf16 (coalesced float4 reads)
    {
        const float4* Xg = (const float4*)(X + (size_t)row0 * DD);
        #pragma unroll
        for (int i = 0; i < 8; ++i) {
            int idx = tid + i * 256;            // 0..2047
            int r = idx >> 5, c4 = idx & 31;
            float4 v = Xg[idx];
            u16x4 u;
            u[0] = f2bf(v.x); u[1] = f2bf(v.y); u[2] = f2bf(v.z); u[3] = f2bf(v.w);
            *(u16x4*)(Xs + r * WPAD + c4 * 4) = u;
        }
    }
    // Stage Wq^T
    #pragma unroll
    for (int i = 0; i < 8; ++i) {
        int c = tid + i * 256;
        int n = c >> 4, k8 = c & 15;
        *(bf8*)(Wb + n * WPAD + k8 * 8) = ((const bf8*)WtT)[c];
    }

    const int lane = tid & 63, wv = tid >> 6;   // wave owns rows wv*16..+15
    const int ln = lane & 15, quad = lane >> 4;
    __syncthreads();

    // A-frags: persistent across the 3 GEMMs (4 k-steps, 16 regs)
    bf8 afr[4];
    #pragma unroll
    for (int s = 0; s < 4; ++s)
        afr[s] = *(const bf8*)(Xs + (wv * 16 + ln) * WPAD + s * 32 + quad * 8);

    const float* biases[3] = { bq, bk, bv };
    unsigned short* outs[3] = { qh, kv, kv + 128 };
    const int strides[3] = { 128, 256, 256 };

    #pragma unroll 1
    for (int g = 0; g < 3; ++g) {
        if (g > 0) {
            __syncthreads();   // all waves done reading Wb for g-1
            const bf8* Wn = (const bf8*)(WtT + g * 16384);
            #pragma unroll
            for (int i = 0; i < 8; ++i) {
                int c = tid + i * 256;
                int n = c >> 4, k8 = c & 15;
                *(bf8*)(Wb + n * WPAD + k8 * 8) = Wn[c];
            }
            __syncthreads();
        }

        f4 acc[8] = {};
        #pragma unroll
        for (int t = 0; t < 8; ++t) {
            bf8 bfr[4];
            #pragma unroll
            for (int s = 0; s < 4; ++s)
                bfr[s] = *(const bf8*)(Wb + (t * 16 + ln) * WPAD + s * 32 + quad * 8);
            #pragma unroll
            for (int s = 0; s < 4; ++s)
                acc[t] = __builtin_amdgcn_mfma_f32_16x16x32_bf16(afr[s], bfr[s], acc[t], 0, 0, 0);
        }

        const float* bias = biases[g];
        unsigned short* Y = outs[g];
        const int st = strides[g];
        #pragma unroll
        for (int t = 0; t < 8; ++t) {
            int col = t * 16 + ln;
            float bc = bias[col];
            #pragma unroll
            for (int r = 0; r < 4; ++r) {
                int row = row0 + wv * 16 + quad * 4 + r;
                Y[(size_t)row * st + col] = f2bf(acc[t][r] + bc);
            }
        }
    }
}

// ---------------------------------------------------------------------------
// Attention, register-resident, S-SPLIT (round-4/6 proven, unchanged).
// 32 lanes/vertex; sp owns half the 17 rows; cross-half via shfl_xor(16).
// V loads issued before softmax (neutral, kept). Unguarded loads; masking
// arithmetic. 8 vertices/block, 4096 blocks; batch pinned to XCD pair.
// ---------------------------------------------------------------------------
__global__ __launch_bounds__(256) void attn_kernel(
    const unsigned short* __restrict__ Qh, const unsigned short* __restrict__ KV,
    const int* __restrict__ nbr, const int* __restrict__ vlen,
    unsigned short* __restrict__ Ctx)
{
    const int tid  = threadIdx.x;
    const int vloc = tid >> 5;        // 0..7
    const int sp   = (tid >> 4) & 1;  // s-half
    const int ln16 = tid & 15;        // 8-dim slot
    const int blk  = blockIdx.x;
    const int b    = (blk & 7) >> 1;                 // batch from XCD pair
    const int j    = ((blk >> 3) << 1) | (blk & 1);  // within-batch group 0..1023
    const int v    = b * NN + j * 8 + vloc;
    const int len  = vlen[v];         // rows 0..len valid (len in [0,16))

    bf8 q8 = *(const bf8*)(Qh + (size_t)v * DD + ln16 * 8);
    float qf[8];
    #pragma unroll
    for (int i = 0; i < 8; ++i) qf[i] = bf2f_s(q8[i]);

    int rows[9];
    {
        const int4* np = (const int4*)(nbr + (size_t)v * KNB);
        if (sp == 0) {
            rows[0] = v;
            int4 a = np[0], c = np[1];
            rows[1] = b * NN + a.x; rows[2] = b * NN + a.y;
            rows[3] = b * NN + a.z; rows[4] = b * NN + a.w;
            rows[5] = b * NN + c.x; rows[6] = b * NN + c.y;
            rows[7] = b * NN + c.z; rows[8] = b * NN + c.w;
        } else {
            int4 a = np[2], c = np[3];
            rows[0] = b * NN + a.x; rows[1] = b * NN + a.y;
            rows[2] = b * NN + a.z; rows[3] = b * NN + a.w;
            rows[4] = b * NN + c.x; rows[5] = b * NN + c.y;
            rows[6] = b * NN + c.z; rows[7] = b * NN + c.w;
            rows[8] = v;            // dummy: s=17 > len always -> weight 0
        }
    }
    const int s0 = sp * 9;

    bf8 k8[9];
    #pragma unroll
    for (int i = 0; i < 9; ++i)
        k8[i] = *(const bf8*)(KV + (size_t)rows[i] * 256 + ln16 * 8);

    float sc[9];
    #pragma unroll
    for (int i = 0; i < 9; ++i) {
        float p = 0.f;
        #pragma unroll
        for (int d = 0; d < 8; ++d) p = fmaf(qf[d], bf2f_s(k8[i][d]), p);
        p += __shfl_xor(p, 1, 4);
        p += __shfl_xor(p, 2, 4);
        sc[i] = (s0 + i <= len) ? p * 0.17677669529663687f : -1.0e9f;  // 1/sqrt(32)
    }

    bf8 v8[9];
    #pragma unroll
    for (int i = 0; i < 9; ++i)
        v8[i] = *(const bf8*)(KV + (size_t)rows[i] * 256 + 128 + ln16 * 8);

    float m = sc[0];
    #pragma unroll
    for (int i = 1; i < 9; ++i) m = fmaxf(m, sc[i]);
    m = fmaxf(m, __shfl_xor(m, 16));
    float sum = 0.f;
    #pragma unroll
    for (int i = 0; i < 9; ++i) {
        float e = __expf(sc[i] - m);    // invalid: exp(-1e9 - m) == 0
        sc[i] = e;
        sum += e;
    }
    sum += __shfl_xor(sum, 16);
    const float inv = 1.f / sum;

    float acc[8] = {};
    #pragma unroll
    for (int i = 0; i < 9; ++i) {
        float w = sc[i] * inv;
        #pragma unroll
        for (int d = 0; d < 8; ++d) acc[d] = fmaf(w, bf2f_s(v8[i][d]), acc[d]);
    }
    #pragma unroll
    for (int d = 0; d < 8; ++d) acc[d] += __shfl_xor(acc[d], 16);

    if (sp == 0) {
        bf8 r;
        #pragma unroll
        for (int d = 0; d < 8; ++d) r[d] = (short)f2bf(acc[d]);
        *(bf8*)(Ctx + (size_t)v * DD + ln16 * 8) = r;
    }
}

// ---------------------------------------------------------------------------
// FOLDED FFN: relu(ctx@Wm + bm) @ W2 + b2   (Wm = Wo@W1, bm = bo@W1 + b1,
// precomputed by qkv's piggyback blocks). 2 GEMMs instead of 3: one fewer
// MFMA phase, one fewer Wb restage, barriers 5 -> 3.
// 64 rows/block, 4 waves; Ct + Wb LDS-staged (round-5 lesson).
// ---------------------------------------------------------------------------
__global__ __launch_bounds__(256) void ffn_kernel(
    const unsigned short* __restrict__ Ctxg, const unsigned short* __restrict__ WmT,
    const unsigned short* __restrict__ W2T, const float* __restrict__ bm,
    const float* __restrict__ b2, float* __restrict__ Out)
{
    __shared__ unsigned short Ct[64 * WPAD];
    __shared__ unsigned short Wb[128 * WPAD];

    const int tid  = threadIdx.x;
    const int row0 = blockIdx.x * 64;

    {
        const bf8* Cg = (const bf8*)(Ctxg + (size_t)row0 * DD);
        #pragma unroll
        for (int i = 0; i < 4; ++i) {
            int idx = tid + i * 256;
            int r = idx >> 4, c8 = idx & 15;
            *(bf8*)(Ct + r * WPAD + c8 * 8) = Cg[idx];
        }
    }
    #pragma unroll
    for (int i = 0; i < 8; ++i) {
        int c = tid + i * 256;
        int n = c >> 4, k8 = c & 15;
        *(bf8*)(Wb + n * WPAD + k8 * 8) = ((const bf8*)WmT)[c];
    }

    const int lane = tid & 63, wv = tid >> 6;
    const int ln = lane & 15, quad = lane >> 4;
    __syncthreads();

    // ---- GEMM 1: h = relu(ctx @ Wm + bm) ----
    {
        bf8 afr[4];
        #pragma unroll
        for (int s = 0; s < 4; ++s)
            afr[s] = *(const bf8*)(Ct + (wv * 16 + ln) * WPAD + s * 32 + quad * 8);

        f4 acc[8] = {};
        #pragma unroll
        for (int t = 0; t < 8; ++t) {
            bf8 bfr[4];
            #pragma unroll
            for (int s = 0; s < 4; ++s)
                bfr[s] = *(const bf8*)(Wb + (t * 16 + ln) * WPAD + s * 32 + quad * 8);
            #pragma unroll
            for (int s = 0; s < 4; ++s)
                acc[t] = __builtin_amdgcn_mfma_f32_16x16x32_bf16(afr[s], bfr[s], acc[t], 0, 0, 0);
        }

        __syncthreads();   // everyone done reading Ct & Wb

        // stage W2^T while Ct is rewritten with relu output
        #pragma unroll
        for (int i = 0; i < 8; ++i) {
            int c = tid + i * 256;
            int n = c >> 4, k8 = c & 15;
            *(bf8*)(Wb + n * WPAD + k8 * 8) = ((const bf8*)W2T)[c];
        }
        #pragma unroll
        for (int t = 0; t < 8; ++t) {
            int col = t * 16 + ln;
            float bc = bm[col];
            #pragma unroll
            for (int r = 0; r < 4; ++r) {
                int rloc = wv * 16 + quad * 4 + r;
                float vv = fmaxf(acc[t][r] + bc, 0.f);
                Ct[rloc * WPAD + col] = f2bf(vv);
            }
        }
        __syncthreads();   // new Ct + Wb visible
    }

    // ---- GEMM 2: out = h @ W2 + b2 ----
    {
        bf8 afr[4];
        #pragma unroll
        for (int s = 0; s < 4; ++s)
            afr[s] = *(const bf8*)(Ct + (wv * 16 + ln) * WPAD + s * 32 + quad * 8);

        f4 acc[8] = {};
        #pragma unroll
        for (int t = 0; t < 8; ++t) {
            bf8 bfr[4];
            #pragma unroll
            for (int s = 0; s < 4; ++s)
                bfr[s] = *(const bf8*)(Wb + (t * 16 + ln) * WPAD + s * 32 + quad * 8);
            #pragma unroll
            for (int s = 0; s < 4; ++s)
                acc[t] = __builtin_amdgcn_mfma_f32_16x16x32_bf16(afr[s], bfr[s], acc[t], 0, 0, 0);
        }

        #pragma unroll
        for (int t = 0; t < 8; ++t) {
            int col = t * 16 + ln;
            float bc = b2[col];
            #pragma unroll
            for (int r = 0; r < 4; ++r) {
                int row = row0 + wv * 16 + quad * 4 + r;
                Out[(size_t)row * DD + col] = acc[t][r] + bc;
            }
        }
    }
}

// ---------------------------------------------------------------------------
extern "C" void kernel_launch(void* const* d_in, const int* in_sizes, int n_in,
                              void* d_out, int out_size, void* d_ws, size_t ws_size,
                              hipStream_t stream)
{
    const float* vf   = (const float*)d_in[0];
    const int*   nbr  = (const int*)  d_in[1];
    const int*   vlen = (const int*)  d_in[2];
    const float* Wq   = (const float*)d_in[3];
    const float* bq   = (const float*)d_in[4];
    const float* Wk   = (const float*)d_in[5];
    const float* bk   = (const float*)d_in[6];
    const float* Wv   = (const float*)d_in[7];
    const float* bv   = (const float*)d_in[8];
    const float* Wo   = (const float*)d_in[9];
    const float* bo   = (const float*)d_in[10];
    const float* W1   = (const float*)d_in[11];
    const float* b1   = (const float*)d_in[12];
    const float* W2   = (const float*)d_in[13];
    const float* b2   = (const float*)d_in[14];

    float* out = (float*)d_out;

    const size_t SZ = (size_t)M_TOT * DD;
    unsigned short* WtT = (unsigned short*)d_ws;    // slots 0..6 (7 x 16384 bf16)
    unsigned short* WmT = WtT + 7 * 16384;          // folded Wo@W1, transposed
    float*          bm  = (float*)(WmT + 16384);    // folded bias (128 fp32)
    unsigned short* qh  = (unsigned short*)(bm + 128);
    unsigned short* kv  = qh + SZ;                  // interleaved K|V, 2*SZ
    unsigned short* ctx = kv + 2 * SZ;

    cvt_wT<<<112, 256, 0, stream>>>(Wq, Wk, Wv, Wo, W1, W2, WtT);

    qkv_kernel<<<515, 256, 0, stream>>>(vf, WtT, bq, bk, bv, W1, bo, b1,
                                        qh, kv, WmT, bm);

    attn_kernel<<<M_TOT / 8, 256, 0, stream>>>(qh, kv, nbr, vlen, ctx);

    ffn_kernel<<<M_TOT / 64, 256, 0, stream>>>(ctx, WmT, WtT + 5 * 16384, bm, b2, out);
}

// Round 8
// 134.350 us; speedup vs baseline: 1.2678x; 1.0091x over previous
//
#include <hip/hip_runtime.h>
#include <math.h>

#define BB 4
#define NN 8192
#define KNB 16
#define DD 128
#define SS 17            // K+1 (self + neighbors)
#define M_TOT (BB*NN)    // 32768
#define WPAD 136         // padded inner stride (elems) for LDS tiles

typedef __attribute__((ext_vector_type(8))) short          bf8;
typedef __attribute__((ext_vector_type(4))) float          f4;
typedef __attribute__((ext_vector_type(4))) unsigned short u16x4;

static __device__ __forceinline__ unsigned short f2bf(float f) {
    unsigned u = __builtin_bit_cast(unsigned, f);
    u += 0x7fffu + ((u >> 16) & 1u);        // round-to-nearest-even
    return (unsigned short)(u >> 16);
}
static __device__ __forceinline__ float bf2f_s(short h) {
    return __builtin_bit_cast(float, (unsigned)(unsigned short)h << 16);
}

// ---------------------------------------------------------------------------
// Convert weights. Blocks 0..95: six 128x128 fp32 weights -> bf16 W^T[n][k]
// (slots 0..5). Blocks 96..111: Wo -> bf16 ROW-MAJOR (slot 6) — B-operand
// for the Wm=Wo@W1 fold GEMM piggybacked on qkv.
// ---------------------------------------------------------------------------
__global__ __launch_bounds__(256) void cvt_wT(
    const float* __restrict__ Wq, const float* __restrict__ Wk,
    const float* __restrict__ Wv, const float* __restrict__ Wo,
    const float* __restrict__ W1, const float* __restrict__ W2,
    unsigned short* __restrict__ out)
{
    const int blk = blockIdx.x;
    if (blk < 96) {
        int m = blk >> 4;
        const float* src = (m == 0) ? Wq : (m == 1) ? Wk : (m == 2) ? Wv
                         : (m == 3) ? Wo : (m == 4) ? W1 : W2;
        unsigned short* dst = out + m * 16384;
        int o = (blk & 15) * 1024 + threadIdx.x * 4;   // output idx [n][k]
        int n = o >> 7, k = o & 127;
        u16x4 r;
        #pragma unroll
        for (int i = 0; i < 4; ++i) r[i] = f2bf(src[(size_t)(k + i) * 128 + n]);
        *(u16x4*)(dst + o) = r;
    } else {
        int o = (blk - 96) * 1024 + threadIdx.x * 4;
        float4 v = *(const float4*)(Wo + o);
        u16x4 r;
        r[0] = f2bf(v.x); r[1] = f2bf(v.y); r[2] = f2bf(v.z); r[3] = f2bf(v.w);
        *(u16x4*)(out + 6 * 16384 + o) = r;
    }
}

// ---------------------------------------------------------------------------
// Fused fp32->bf16 convert + QKV projection. ROUND-8: 128-row tiles,
// 512 threads (8 waves), 256 main blocks — halves total barrier-drain
// instances and weight L2 re-reads vs 64-row tiles; LDS 34.8+34.8=69.6 KB
// -> 2 blocks/CU = 16 waves/CU (was 12).
// Round-5 lesson kept: B-frags NEVER read from global (fragment lane
// pattern shatters ~16x in L2); stage coalesced into LDS.
// K and V outputs INTERLEAVED per row: kv[row][0:128]=K, [128:256]=V.
// Fragment maps (m89-verified): A[m=lane&15][k=quad*8+j],
// B[k=quad*8+j][n=lane&15], D[row=quad*4+r][col=lane&15].
// PIGGYBACK blocks: 256 = WmT=(Wo@W1)^T (128 rows), 257 = bm=bo@W1+b1.
// ---------------------------------------------------------------------------
__global__ __launch_bounds__(512) void qkv_kernel(
    const float* __restrict__ X, const unsigned short* __restrict__ WtT,
    const float* __restrict__ bq, const float* __restrict__ bk,
    const float* __restrict__ bv,
    const float* __restrict__ W1f, const float* __restrict__ bo,
    const float* __restrict__ b1,
    unsigned short* __restrict__ qh, unsigned short* __restrict__ kv,
    unsigned short* __restrict__ WmT, float* __restrict__ bm)
{
    __shared__ unsigned short Xs[128 * WPAD];   // 34816 B
    __shared__ unsigned short Wb[128 * WPAD];   // 34816 B

    const int tid = threadIdx.x;
    const int blk = blockIdx.x;
    const int lane = tid & 63, wv = tid >> 6;   // wave owns rows wv*16..+15
    const int ln = lane & 15, quad = lane >> 4;

    if (blk >= 256) {
        if (blk == 257) {           // bm[e] = b1[e] + sum_d bo[d]*W1[d][e]
            if (tid < 128) {
                float a = b1[tid];
                for (int d = 0; d < 128; ++d)
                    a = fmaf(bo[d], W1f[(size_t)d * 128 + tid], a);
                bm[tid] = a;
            }
            return;
        }
        // blk==256: WmT[e][hk] = sum_d W1T[e][d] * Wo[hk][d]  (128 rows)
        {
            const bf8* Ag = (const bf8*)(WtT + 4 * 16384);
            const bf8* Bg = (const bf8*)(WtT + 6 * 16384);
            #pragma unroll
            for (int i = 0; i < 4; ++i) {
                int c = tid + i * 512;          // 0..2047
                int r = c >> 4, c8 = c & 15;
                *(bf8*)(Xs + r * WPAD + c8 * 8) = Ag[c];
                *(bf8*)(Wb + r * WPAD + c8 * 8) = Bg[c];
            }
        }
        __syncthreads();
        bf8 afr[4];
        #pragma unroll
        for (int s = 0; s < 4; ++s)
            afr[s] = *(const bf8*)(Xs + (wv * 16 + ln) * WPAD + s * 32 + quad * 8);
        f4 acc[8] = {};
        #pragma unroll
        for (int t = 0; t < 8; ++t) {
            bf8 bfr[4];
            #pragma unroll
            for (int s = 0; s < 4; ++s)
                bfr[s] = *(const bf8*)(Wb + (t * 16 + ln) * WPAD + s * 32 + quad * 8);
            #pragma unroll
            for (int s = 0; s < 4; ++s)
                acc[t] = __builtin_amdgcn_mfma_f32_16x16x32_bf16(afr[s], bfr[s], acc[t], 0, 0, 0);
        }
        #pragma unroll
        for (int t = 0; t < 8; ++t) {
            int col = t * 16 + ln;
            #pragma unroll
            for (int r = 0; r < 4; ++r) {
                int row = wv * 16 + quad * 4 + r;
                WmT[(size_t)row * 128 + col] = f2bf(acc[t][r]);
            }
        }
        return;
    }

    const int row0 = blk * 128;

    // Stage X tile fp32 -> bf16 (coalesced float4 reads): 128 rows
    {
        const float4* Xg = (const float4*)(X + (size_t)row0 * DD);
        #pragma unroll
        for (int i = 0; i < 8; ++i) {
            int idx = tid + i * 512;            // 0..4095
            int r = idx >> 5, c4 = idx & 31;
            float4 v = Xg[idx];
            u16x4 u;
            u[0] = f2bf(v.x); u[1] = f2bf(v.y); u[2] = f2bf(v.z); u[3] = f2bf(v.w);
            *(u16x4*)(Xs + r * WPAD + c4 * 4) = u;
        }
    }
    // Stage Wq^T
    #pragma unroll
    for (int i = 0; i < 4; ++i) {
        int c = tid + i * 512;                  // 0..2047
        int n = c >> 4, k8 = c & 15;
        *(bf8*)(Wb + n * WPAD + k8 * 8) = ((const bf8*)WtT)[c];
    }
    __syncthreads();

    // A-frags: persistent across the 3 GEMMs (4 k-steps, 16 regs)
    bf8 afr[4];
    #pragma unroll
    for (int s = 0; s < 4; ++s)
        afr[s] = *(const bf8*)(Xs + (wv * 16 + ln) * WPAD + s * 32 + quad * 8);

    const float* biases[3] = { bq, bk, bv };
    unsigned short* outs[3] = { qh, kv, kv + 128 };
    const int strides[3] = { 128, 256, 256 };

    #pragma unroll 1
    for (int g = 0; g < 3; ++g) {
        if (g > 0) {
            __syncthreads();   // all waves done reading Wb for g-1
            const bf8* Wn = (const bf8*)(WtT + g * 16384);
            #pragma unroll
            for (int i = 0; i < 4; ++i) {
                int c = tid + i * 512;
                int n = c >> 4, k8 = c & 15;
                *(bf8*)(Wb + n * WPAD + k8 * 8) = Wn[c];
            }
            __syncthreads();
        }

        f4 acc[8] = {};
        #pragma unroll
        for (int t = 0; t < 8; ++t) {
            bf8 bfr[4];
            #pragma unroll
            for (int s = 0; s < 4; ++s)
                bfr[s] = *(const bf8*)(Wb + (t * 16 + ln) * WPAD + s * 32 + quad * 8);
            #pragma unroll
            for (int s = 0; s < 4; ++s)
                acc[t] = __builtin_amdgcn_mfma_f32_16x16x32_bf16(afr[s], bfr[s], acc[t], 0, 0, 0);
        }

        const float* bias = biases[g];
        unsigned short* Y = outs[g];
        const int st = strides[g];
        #pragma unroll
        for (int t = 0; t < 8; ++t) {
            int col = t * 16 + ln;
            float bc = bias[col];
            #pragma unroll
            for (int r = 0; r < 4; ++r) {
                int row = row0 + wv * 16 + quad * 4 + r;
                Y[(size_t)row * st + col] = f2bf(acc[t][r] + bc);
            }
        }
    }
}

// ---------------------------------------------------------------------------
// Attention, register-resident, S-SPLIT (round-4/6 proven). 32 lanes/vertex;
// sp owns half the 17 rows; cross-half via shfl_xor(16). ROUND-8: minimum-
// liveness ordering (V loads after softmax — hoist was neutral twice, frees
// ~36 VGPR) + __launch_bounds__(256,4) pinning 4 waves/EU (16 waves/CU).
// Loads unguarded (round-1 lesson); masking arithmetic.
// 8 vertices/block, 4096 blocks; batch pinned to XCD pair.
// ---------------------------------------------------------------------------
__global__ __launch_bounds__(256, 4) void attn_kernel(
    const unsigned short* __restrict__ Qh, const unsigned short* __restrict__ KV,
    const int* __restrict__ nbr, const int* __restrict__ vlen,
    unsigned short* __restrict__ Ctx)
{
    const int tid  = threadIdx.x;
    const int vloc = tid >> 5;        // 0..7
    const int sp   = (tid >> 4) & 1;  // s-half
    const int ln16 = tid & 15;        // 8-dim slot
    const int blk  = blockIdx.x;
    const int b    = (blk & 7) >> 1;                 // batch from XCD pair
    const int j    = ((blk >> 3) << 1) | (blk & 1);  // within-batch group 0..1023
    const int v    = b * NN + j * 8 + vloc;
    const int len  = vlen[v];         // rows 0..len valid (len in [0,16))

    bf8 q8 = *(const bf8*)(Qh + (size_t)v * DD + ln16 * 8);
    float qf[8];
    #pragma unroll
    for (int i = 0; i < 8; ++i) qf[i] = bf2f_s(q8[i]);

    int rows[9];
    {
        const int4* np = (const int4*)(nbr + (size_t)v * KNB);
        if (sp == 0) {
            rows[0] = v;
            int4 a = np[0], c = np[1];
            rows[1] = b * NN + a.x; rows[2] = b * NN + a.y;
            rows[3] = b * NN + a.z; rows[4] = b * NN + a.w;
            rows[5] = b * NN + c.x; rows[6] = b * NN + c.y;
            rows[7] = b * NN + c.z; rows[8] = b * NN + c.w;
        } else {
            int4 a = np[2], c = np[3];
            rows[0] = b * NN + a.x; rows[1] = b * NN + a.y;
            rows[2] = b * NN + a.z; rows[3] = b * NN + a.w;
            rows[4] = b * NN + c.x; rows[5] = b * NN + c.y;
            rows[6] = b * NN + c.z; rows[7] = b * NN + c.w;
            rows[8] = v;            // dummy: s=17 > len always -> weight 0
        }
    }
    const int s0 = sp * 9;

    // K loads (batched, unguarded)
    bf8 k8[9];
    #pragma unroll
    for (int i = 0; i < 9; ++i)
        k8[i] = *(const bf8*)(KV + (size_t)rows[i] * 256 + ln16 * 8);

    float sc[9];
    #pragma unroll
    for (int i = 0; i < 9; ++i) {
        float p = 0.f;
        #pragma unroll
        for (int d = 0; d < 8; ++d) p = fmaf(qf[d], bf2f_s(k8[i][d]), p);
        p += __shfl_xor(p, 1, 4);
        p += __shfl_xor(p, 2, 4);
        sc[i] = (s0 + i <= len) ? p * 0.17677669529663687f : -1.0e9f;  // 1/sqrt(32)
    }

    // Softmax across both halves: max/sum via shfl_xor(16).
    float m = sc[0];
    #pragma unroll
    for (int i = 1; i < 9; ++i) m = fmaxf(m, sc[i]);
    m = fmaxf(m, __shfl_xor(m, 16));
    float sum = 0.f;
    #pragma unroll
    for (int i = 0; i < 9; ++i) {
        float e = __expf(sc[i] - m);    // invalid: exp(-1e9 - m) == 0
        sc[i] = e;
        sum += e;
    }
    sum += __shfl_xor(sum, 16);
    const float inv = 1.f / sum;

    // Pass 2: weighted V accumulate (V at +128 elems = imm offset)
    float acc[8] = {};
    #pragma unroll
    for (int i = 0; i < 9; ++i) {
        bf8 v8 = *(const bf8*)(KV + (size_t)rows[i] * 256 + 128 + ln16 * 8);
        float w = sc[i] * inv;
        #pragma unroll
        for (int d = 0; d < 8; ++d) acc[d] = fmaf(w, bf2f_s(v8[d]), acc[d]);
    }
    #pragma unroll
    for (int d = 0; d < 8; ++d) acc[d] += __shfl_xor(acc[d], 16);

    if (sp == 0) {
        bf8 r;
        #pragma unroll
        for (int d = 0; d < 8; ++d) r[d] = (short)f2bf(acc[d]);
        *(bf8*)(Ctx + (size_t)v * DD + ln16 * 8) = r;
    }
}

// ---------------------------------------------------------------------------
// FOLDED FFN: relu(ctx@Wm + bm) @ W2 + b2 (round-7 proven). 2 GEMMs.
// 64 rows/block, 4 waves; Ct + Wb LDS-staged (round-5 lesson).
// ---------------------------------------------------------------------------
__global__ __launch_bounds__(256) void ffn_kernel(
    const unsigned short* __restrict__ Ctxg, const unsigned short* __restrict__ WmT,
    const unsigned short* __restrict__ W2T, const float* __restrict__ bm,
    const float* __restrict__ b2, float* __restrict__ Out)
{
    __shared__ unsigned short Ct[64 * WPAD];
    __shared__ unsigned short Wb[128 * WPAD];

    const int tid  = threadIdx.x;
    const int row0 = blockIdx.x * 64;

    {
        const bf8* Cg = (const bf8*)(Ctxg + (size_t)row0 * DD);
        #pragma unroll
        for (int i = 0; i < 4; ++i) {
            int idx = tid + i * 256;
            int r = idx >> 4, c8 = idx & 15;
            *(bf8*)(Ct + r * WPAD + c8 * 8) = Cg[idx];
        }
    }
    #pragma unroll
    for (int i = 0; i < 8; ++i) {
        int c = tid + i * 256;
        int n = c >> 4, k8 = c & 15;
        *(bf8*)(Wb + n * WPAD + k8 * 8) = ((const bf8*)WmT)[c];
    }

    const int lane = tid & 63, wv = tid >> 6;
    const int ln = lane & 15, quad = lane >> 4;
    __syncthreads();

    // ---- GEMM 1: h = relu(ctx @ Wm + bm) ----
    {
        bf8 afr[4];
        #pragma unroll
        for (int s = 0; s < 4; ++s)
            afr[s] = *(const bf8*)(Ct + (wv * 16 + ln) * WPAD + s * 32 + quad * 8);

        f4 acc[8] = {};
        #pragma unroll
        for (int t = 0; t < 8; ++t) {
            bf8 bfr[4];
            #pragma unroll
            for (int s = 0; s < 4; ++s)
                bfr[s] = *(const bf8*)(Wb + (t * 16 + ln) * WPAD + s * 32 + quad * 8);
            #pragma unroll
            for (int s = 0; s < 4; ++s)
                acc[t] = __builtin_amdgcn_mfma_f32_16x16x32_bf16(afr[s], bfr[s], acc[t], 0, 0, 0);
        }

        __syncthreads();   // everyone done reading Ct & Wb

        // stage W2^T while Ct is rewritten with relu output
        #pragma unroll
        for (int i = 0; i < 8; ++i) {
            int c = tid + i * 256;
            int n = c >> 4, k8 = c & 15;
            *(bf8*)(Wb + n * WPAD + k8 * 8) = ((const bf8*)W2T)[c];
        }
        #pragma unroll
        for (int t = 0; t < 8; ++t) {
            int col = t * 16 + ln;
            float bc = bm[col];
            #pragma unroll
            for (int r = 0; r < 4; ++r) {
                int rloc = wv * 16 + quad * 4 + r;
                float vv = fmaxf(acc[t][r] + bc, 0.f);
                Ct[rloc * WPAD + col] = f2bf(vv);
            }
        }
        __syncthreads();   // new Ct + Wb visible
    }

    // ---- GEMM 2: out = h @ W2 + b2 ----
    {
        bf8 afr[4];
        #pragma unroll
        for (int s = 0; s < 4; ++s)
            afr[s] = *(const bf8*)(Ct + (wv * 16 + ln) * WPAD + s * 32 + quad * 8);

        f4 acc[8] = {};
        #pragma unroll
        for (int t = 0; t < 8; ++t) {
            bf8 bfr[4];
            #pragma unroll
            for (int s = 0; s < 4; ++s)
                bfr[s] = *(const bf8*)(Wb + (t * 16 + ln) * WPAD + s * 32 + quad * 8);
            #pragma unroll
            for (int s = 0; s < 4; ++s)
                acc[t] = __builtin_amdgcn_mfma_f32_16x16x32_bf16(afr[s], bfr[s], acc[t], 0, 0, 0);
        }

        #pragma unroll
        for (int t = 0; t < 8; ++t) {
            int col = t * 16 + ln;
            float bc = b2[col];
            #pragma unroll
            for (int r = 0; r < 4; ++r) {
                int row = row0 + wv * 16 + quad * 4 + r;
                Out[(size_t)row * DD + col] = acc[t][r] + bc;
            }
        }
    }
}

// ---------------------------------------------------------------------------
extern "C" void kernel_launch(void* const* d_in, const int* in_sizes, int n_in,
                              void* d_out, int out_size, void* d_ws, size_t ws_size,
                              hipStream_t stream)
{
    const float* vf   = (const float*)d_in[0];
    const int*   nbr  = (const int*)  d_in[1];
    const int*   vlen = (const int*)  d_in[2];
    const float* Wq   = (const float*)d_in[3];
    const float* bq   = (const float*)d_in[4];
    const float* Wk   = (const float*)d_in[5];
    const float* bk   = (const float*)d_in[6];
    const float* Wv   = (const float*)d_in[7];
    const float* bv   = (const float*)d_in[8];
    const float* Wo   = (const float*)d_in[9];
    const float* bo   = (const float*)d_in[10];
    const float* W1   = (const float*)d_in[11];
    const float* b1   = (const float*)d_in[12];
    const float* W2   = (const float*)d_in[13];
    const float* b2   = (const float*)d_in[14];

    float* out = (float*)d_out;

    const size_t SZ = (size_t)M_TOT * DD;
    unsigned short* WtT = (unsigned short*)d_ws;    // slots 0..6 (7 x 16384 bf16)
    unsigned short* WmT = WtT + 7 * 16384;          // folded Wo@W1, transposed
    float*          bm  = (float*)(WmT + 16384);    // folded bias (128 fp32)
    unsigned short* qh  = (unsigned short*)(bm + 128);
    unsigned short* kv  = qh + SZ;                  // interleaved K|V, 2*SZ
    unsigned short* ctx = kv + 2 * SZ;

    cvt_wT<<<112, 256, 0, stream>>>(Wq, Wk, Wv, Wo, W1, W2, WtT);

    qkv_kernel<<<258, 512, 0, stream>>>(vf, WtT, bq, bk, bv, W1, bo, b1,
                                        qh, kv, WmT, bm);

    attn_kernel<<<M_TOT / 8, 256, 0, stream>>>(qh, kv, nbr, vlen, ctx);

    ffn_kernel<<<M_TOT / 64, 256, 0, stream>>>(ctx, WmT, WtT + 5 * 16384, bm, b2, out);
}